// Round 5
// baseline (284.156 us; speedup 1.0000x reference)
//
#include <hip/hip_runtime.h>

// Causal cumulative mean: out[b,t,c] = (1/(t+1)) * sum_{s<=t} x[b,s,c]
// x: (B=8, T=4096, C=1024) fp32. SINGLE-KERNEL decoupled-lookback scan.
//  - grid (NCHUNK=64, B=8) = 512 blocks of 256 threads; thread owns 4 channels.
//  - phase 1: block sums its 64-timestep chunk -> publishes aggregate vector
//    (agent-scope atomic stores) + release flag.
//  - lookback: parallel spin until ALL predecessor flags set (thread i polls
//    flag i, __syncthreads_and), then pipelined independent-load sum of all
//    predecessor aggregates (no serial flag-walk, no inclusive-state chain).
//  - phase 2: re-read chunk (L3-hot: x=128MB < 256MB L3), running prefix,
//    out = run * rcp(t+1).
// Safety: __launch_bounds__(256,4) => >=4 blocks/CU capacity (1024) >= 512
// blocks, all co-resident; only predecessors awaited => no deadlock. Poison
// 0xAAAAAAAA != 1 reads as not-ready, so no flag-zeroing pass is needed.

constexpr int B_SZ   = 8;
constexpr int T_SZ   = 4096;
constexpr int C_SZ   = 1024;
constexpr int CHUNK  = 64;
constexpr int NCHUNK = T_SZ / CHUNK;   // 64
constexpr int C4     = C_SZ / 4;       // 256 threads/block

#define SCOPE_AGENT __HIP_MEMORY_SCOPE_AGENT

__global__ __launch_bounds__(C4, 4) void cummean_lookback(
    const float4* __restrict__ x, float4* __restrict__ out,
    unsigned* __restrict__ ws) {
    const int k = blockIdx.x;   // chunk
    const int b = blockIdx.y;   // batch
    const int c = threadIdx.x;  // float4-channel index

    // ws layout: aggs[B][NCHUNK][C_SZ] (uints=float bits), then flags[B][NCHUNK]
    unsigned* aggs  = ws;
    unsigned* flags = ws + (size_t)B_SZ * NCHUNK * C_SZ;

    // ---- phase 1: chunk sum (two accumulators for ILP) ----
    const size_t base = (size_t)(b * T_SZ + k * CHUNK) * C4 + c;
    const float4* xp = x + base;
    float sx=0.f,sy=0.f,sz=0.f,sw=0.f, tx=0.f,ty=0.f,tz=0.f,tw=0.f;
#pragma unroll 8
    for (int t = 0; t < CHUNK; t += 2) {
        float4 a = xp[(size_t)t * C4];
        float4 d = xp[(size_t)(t + 1) * C4];
        sx += a.x; sy += a.y; sz += a.z; sw += a.w;
        tx += d.x; ty += d.y; tz += d.z; tw += d.w;
    }
    const float agx = sx + tx, agy = sy + ty, agz = sz + tz, agw = sw + tw;

    // ---- publish aggregate (agent-scope so cross-XCD readers see it) ----
    unsigned* ag = aggs + (size_t)(b * NCHUNK + k) * C_SZ + c * 4;
    __hip_atomic_store(ag + 0, __float_as_uint(agx), __ATOMIC_RELAXED, SCOPE_AGENT);
    __hip_atomic_store(ag + 1, __float_as_uint(agy), __ATOMIC_RELAXED, SCOPE_AGENT);
    __hip_atomic_store(ag + 2, __float_as_uint(agz), __ATOMIC_RELAXED, SCOPE_AGENT);
    __hip_atomic_store(ag + 3, __float_as_uint(agw), __ATOMIC_RELAXED, SCOPE_AGENT);
    __syncthreads();   // all stores complete (waitcnt before barrier)
    if (c == 0)
        __hip_atomic_store(&flags[b * NCHUNK + k], 1u, __ATOMIC_RELEASE, SCOPE_AGENT);

    // ---- lookback: wait for all predecessors, then parallel aggregate sum ----
    float rx = 0.f, ry = 0.f, rz = 0.f, rw = 0.f;
    if (k > 0) {
        int ready;
        do {
            int ok = 1;
            if (c < k) {
                unsigned f = __hip_atomic_load(&flags[b * NCHUNK + c],
                                               __ATOMIC_ACQUIRE, SCOPE_AGENT);
                ok = (f == 1u);
            }
            ready = __syncthreads_and(ok);
        } while (!ready);

        const unsigned* ap = aggs + (size_t)b * NCHUNK * C_SZ + c * 4;
#pragma unroll 2
        for (int j = 0; j < k; ++j) {
            const unsigned* a = ap + (size_t)j * C_SZ;
            rx += __uint_as_float(__hip_atomic_load(a + 0, __ATOMIC_RELAXED, SCOPE_AGENT));
            ry += __uint_as_float(__hip_atomic_load(a + 1, __ATOMIC_RELAXED, SCOPE_AGENT));
            rz += __uint_as_float(__hip_atomic_load(a + 2, __ATOMIC_RELAXED, SCOPE_AGENT));
            rw += __uint_as_float(__hip_atomic_load(a + 3, __ATOMIC_RELAXED, SCOPE_AGENT));
        }
    }

    // ---- phase 2: in-chunk running prefix, scaled write ----
    float4 run; run.x = rx; run.y = ry; run.z = rz; run.w = rw;
    float4* op = out + base;
    const int t0 = k * CHUNK;
#pragma unroll 4
    for (int t = 0; t < CHUNK; ++t) {
        float4 v = xp[(size_t)t * C4];
        run.x += v.x; run.y += v.y; run.z += v.z; run.w += v.w;
        const float inv = __builtin_amdgcn_rcpf((float)(t0 + t + 1));
        float4 o;
        o.x = run.x * inv; o.y = run.y * inv; o.z = run.z * inv; o.w = run.w * inv;
        op[(size_t)t * C4] = o;
    }
}

extern "C" void kernel_launch(void* const* d_in, const int* in_sizes, int n_in,
                              void* d_out, int out_size, void* d_ws, size_t ws_size,
                              hipStream_t stream) {
    const float4* x   = (const float4*)d_in[0];
    float4*       out = (float4*)d_out;
    unsigned*     ws  = (unsigned*)d_ws;   // 2MB aggs + 2KB flags

    dim3 grid(NCHUNK, B_SZ);
    cummean_lookback<<<grid, C4, 0, stream>>>(x, out, ws);
}

// Round 13
// 256.131 us; speedup vs baseline: 1.1094x; 1.1094x over previous
//
#include <hip/hip_runtime.h>

// Causal cumulative mean: out[b,t,c] = (1/(t+1)) * sum_{s<=t} x[b,s,c]
// x: (B=8, T=4096, C=1024) fp32. Two-kernel, spin-free chunked scan:
//   K1: part[b][k][c] = sum of x over chunk k (CHUNK=32). 1024 blocks, 4/CU.
//   K2: run = sum of predecessor partials (L2-resident 4MB, guaranteed ready
//       by the kernel boundary -- no flags, no spinning), then in-chunk
//       running prefix over a re-read of x (L3-hot), out = run * rcp(t+1)
//       via NONTEMPORAL stores so the out stream doesn't evict x from L3.
// Round-5 lesson: decoupled-lookback spin ran at 2 TB/s (25% peak) despite
// ideal traffic -- the acquire-spin + all-predecessor convoy cost ~80us.
// Kernel-boundary synchronization is cheaper than in-kernel waiting here.

constexpr int B_SZ   = 8;
constexpr int T_SZ   = 4096;
constexpr int C_SZ   = 1024;
constexpr int CHUNK  = 32;
constexpr int NCHUNK = T_SZ / CHUNK;   // 128
constexpr int C4     = C_SZ / 4;       // 256 threads/block

typedef float f32x4 __attribute__((ext_vector_type(4)));

__global__ __launch_bounds__(C4) void cummean_partial(
    const float4* __restrict__ x, float4* __restrict__ part) {
    const int k = blockIdx.x, b = blockIdx.y, c = threadIdx.x;
    const float4* xp = x + (size_t)(b * T_SZ + k * CHUNK) * C4 + c;
    float sx=0.f,sy=0.f,sz=0.f,sw=0.f, tx=0.f,ty=0.f,tz=0.f,tw=0.f;
#pragma unroll 8
    for (int t = 0; t < CHUNK; t += 2) {
        float4 a = xp[(size_t)t * C4];
        float4 d = xp[(size_t)(t + 1) * C4];
        sx += a.x; sy += a.y; sz += a.z; sw += a.w;
        tx += d.x; ty += d.y; tz += d.z; tw += d.w;
    }
    float4 s; s.x = sx + tx; s.y = sy + ty; s.z = sz + tz; s.w = sw + tw;
    part[(size_t)(b * NCHUNK + k) * C4 + c] = s;
}

__global__ __launch_bounds__(C4) void cummean_scan(
    const float4* __restrict__ x, const float4* __restrict__ part,
    float4* __restrict__ out) {
    const int k = blockIdx.x, b = blockIdx.y, c = threadIdx.x;

    // Exclusive prefix of chunk partials -- independent pipelined loads from
    // the 4MB L2-resident partial array. Two accumulators for ILP.
    float rx=0.f, ry=0.f, rz=0.f, rw=0.f, qx=0.f, qy=0.f, qz=0.f, qw=0.f;
    const float4* pp = part + (size_t)b * NCHUNK * C4 + c;
    int j = 0;
    for (; j + 1 < k; j += 2) {
        float4 a = pp[(size_t)j * C4];
        float4 d = pp[(size_t)(j + 1) * C4];
        rx += a.x; ry += a.y; rz += a.z; rw += a.w;
        qx += d.x; qy += d.y; qz += d.z; qw += d.w;
    }
    if (j < k) {
        float4 a = pp[(size_t)j * C4];
        rx += a.x; ry += a.y; rz += a.z; rw += a.w;
    }

    float4 run; run.x = rx + qx; run.y = ry + qy; run.z = rz + qz; run.w = rw + qw;

    const size_t base = (size_t)(b * T_SZ + k * CHUNK) * C4 + c;
    const float4* xp = x + base;
    f32x4*        op = (f32x4*)(out + base);
    const int t0 = k * CHUNK;
#pragma unroll 8
    for (int t = 0; t < CHUNK; ++t) {
        float4 v = xp[(size_t)t * C4];
        run.x += v.x; run.y += v.y; run.z += v.z; run.w += v.w;
        const float inv = __builtin_amdgcn_rcpf((float)(t0 + t + 1));
        f32x4 o;
        o[0] = run.x * inv; o[1] = run.y * inv; o[2] = run.z * inv; o[3] = run.w * inv;
        __builtin_nontemporal_store(o, op + (size_t)t * C4);  // keep x in L3
    }
}

extern "C" void kernel_launch(void* const* d_in, const int* in_sizes, int n_in,
                              void* d_out, int out_size, void* d_ws, size_t ws_size,
                              hipStream_t stream) {
    const float4* x    = (const float4*)d_in[0];
    float4*       out  = (float4*)d_out;
    float4*       part = (float4*)d_ws;   // B*NCHUNK*C floats = 4 MB

    dim3 grid(NCHUNK, B_SZ);
    cummean_partial<<<grid, C4, 0, stream>>>(x, part);
    cummean_scan<<<grid, C4, 0, stream>>>(x, part, out);
}